// Round 16
// baseline (604.891 us; speedup 1.0000x reference)
//
#include <hip/hip_runtime.h>
#include <math.h>

#ifndef M_PI
#define M_PI 3.14159265358979323846
#endif

static constexpr int N_NODES = 20000;
static constexpr int N_EDGES = 320000;
static constexpr int NLAYER  = 3;
static constexpr int NB_SCAN = (N_NODES + 255) / 256;  // 79
static constexpr int TAB_T   = 1024;                   // filter lookup rows (L2-resident)

typedef _Float16 f16;
typedef __attribute__((ext_vector_type(2))) _Float16 f16x2;
typedef __attribute__((ext_vector_type(8))) _Float16 f16x8;
typedef __attribute__((ext_vector_type(4))) float f32x4;

// ---------------- CSR build ----------------
__global__ void k_hist(const int* __restrict__ idx_i, int* __restrict__ cnt) {
  int e = blockIdx.x * 256 + threadIdx.x;
  if (e < N_EDGES) atomicAdd(&cnt[idx_i[e]], 1);
}

__global__ void k_scan_blk(const int* __restrict__ cnt, int* __restrict__ incl,
                           int* __restrict__ bsum) {
  __shared__ int buf[256];
  int t = threadIdx.x;
  int i = blockIdx.x * 256 + t;
  int v = (i < N_NODES) ? cnt[i] : 0;
  buf[t] = v;
  __syncthreads();
  #pragma unroll
  for (int off = 1; off < 256; off <<= 1) {
    int x = (t >= off) ? buf[t - off] : 0;
    __syncthreads();
    buf[t] += x;
    __syncthreads();
  }
  if (i < N_NODES) incl[i] = buf[t];
  if (t == 255) bsum[blockIdx.x] = buf[255];
}

__global__ void k_scan_top(int* __restrict__ bsum) {
  __shared__ int buf[128];
  int t = threadIdx.x;
  int v = (t < NB_SCAN) ? bsum[t] : 0;
  buf[t] = v;
  __syncthreads();
  #pragma unroll
  for (int off = 1; off < 128; off <<= 1) {
    int x = (t >= off) ? buf[t - off] : 0;
    __syncthreads();
    buf[t] += x;
    __syncthreads();
  }
  if (t <= NB_SCAN) bsum[t] = buf[t] - v;  // exclusive; t==NB_SCAN -> total
}

__global__ void k_scan_add(const int* __restrict__ cnt, const int* __restrict__ incl,
                           const int* __restrict__ bsum, int* __restrict__ rs,
                           int* __restrict__ cur) {
  int i = blockIdx.x * 256 + threadIdx.x;
  if (i < N_NODES) {
    int v = bsum[blockIdx.x] + incl[i] - cnt[i];
    rs[i] = v;
    cur[i] = v;
  }
  if (i == 0) rs[N_NODES] = bsum[NB_SCAN];
}

// ---------------- fill + edge geometry (merged): geo = {d, dx, dy, dz} ----------------
__global__ void k_fill_geom(const int* __restrict__ idx_all, const float* __restrict__ pos,
                            int* __restrict__ cur, float4* __restrict__ geo,
                            int* __restrict__ jperm) {
  int e = blockIdx.x * 256 + threadIdx.x;
  if (e >= N_EDGES) return;
  int i = idx_all[e];
  int j = idx_all[N_EDGES + e];
  int p = atomicAdd(&cur[i], 1);
  float rx = pos[j*3+0] - pos[i*3+0];
  float ry = pos[j*3+1] - pos[i*3+1];
  float rz = pos[j*3+2] - pos[i*3+2];
  float d = sqrtf(rx*rx + ry*ry + rz*rz);
  d = fmaxf(d, 1e-8f);
  float inv = 1.0f / d;
  geo[p] = make_float4(d, rx*inv, ry*inv, rz*inv);
  jperm[p] = j;
}

// ---------------- weight transpose + filter table (merged prep) ----------------
struct WJob { const float* src; f16* dst; int kshift; int ld; int col0; int nk; };
struct WJobs { WJob j[16]; };

__global__ __launch_bounds__(256) void k_prep(WJobs jb, const float* __restrict__ filt_w,
                                              const float* __restrict__ filt_b,
                                              f16* __restrict__ tab) {
  if (blockIdx.y < 16) {
    WJob w = jb.j[blockIdx.y];
    int t = blockIdx.x * 256 + threadIdx.x;
    if (t >= w.nk) return;
    int K = 1 << w.kshift;
    int n = t >> w.kshift;
    int k = t & (K - 1);
    w.dst[t] = (f16)w.src[(size_t)k * w.ld + w.col0 + n];
    return;
  }
  if (blockIdx.x >= 128) return;
  const int t = (blockIdx.y - 16) * 128 + blockIdx.x;
  __shared__ float ph[64];
  const int tid = threadIdx.x;
  const float dist = 5.0f * (float)t / (float)(TAB_T - 1);
  const float delta = 5.0f / 63.0f;
  const float coeff = -0.5f / (delta * delta);
  if (tid < 64) {
    float u = dist - delta * (float)tid;
    ph[tid] = expf(coeff * u * u);
  }
  __syncthreads();
  float xc = dist * 0.2f;
  float fc = (xc < 1.0f) ? 0.5f * (cosf((float)M_PI * xc) + 1.0f) : 0.0f;
  for (int n = tid; n < 384; n += 256) {
    float acc = 0.f;
    #pragma unroll
    for (int k = 0; k < 64; ++k) acc += ph[k] * filt_w[k * 384 + n];
    float v = (acc + filt_b[n]) * fc;
    v = fminf(fmaxf(v, -5.0f), 5.0f);
    tab[(size_t)t * 384 + n] = (f16)v;
  }
}

// ======== embed + inter MLP (layer 0) ========
__global__ __launch_bounds__(256) void k_embed_i(
    const float* __restrict__ z, const f16* __restrict__ Win, const float* __restrict__ bin,
    const f16* __restrict__ Wi1, const float* __restrict__ bi1,
    const f16* __restrict__ Wi2, const float* __restrict__ bi2,
    float* __restrict__ q, f16* __restrict__ xout) {
  __shared__ __align__(16) char pool[16896];
  f16* QS  = (f16*)pool;            // [32][132]
  f16* H2S = (f16*)(pool + 8448);   // [32][132]
  const int tid = threadIdx.x;
  const int wave = tid >> 6, lane = tid & 63;
  const int lr = lane & 15, lk = lane >> 4;
  const int wm = (wave & 1) * 16, wn = (wave >> 1) * 64;
  const int n0 = blockIdx.x * 32;

  f32x4 accP[4] = {};
  #pragma unroll
  for (int kk = 0; kk < 2; ++kk) {
    const float* zp = z + (size_t)(n0 + wm + lr) * 64 + kk * 32 + lk * 8;
    float4 v0 = ((const float4*)zp)[0];
    float4 v1 = ((const float4*)zp)[1];
    f16x8 af;
    af[0]=(f16)v0.x; af[1]=(f16)v0.y; af[2]=(f16)v0.z; af[3]=(f16)v0.w;
    af[4]=(f16)v1.x; af[5]=(f16)v1.y; af[6]=(f16)v1.z; af[7]=(f16)v1.w;
    f16x8 bf[4];
    #pragma unroll
    for (int nt = 0; nt < 4; ++nt)
      bf[nt] = *(const f16x8*)&Win[(size_t)(wn + nt * 16 + lr) * 64 + kk * 32 + lk * 8];
    #pragma unroll
    for (int nt = 0; nt < 4; ++nt)
      accP[nt] = __builtin_amdgcn_mfma_f32_16x16x32_f16(af, bf[nt], accP[nt], 0, 0, 0);
  }
  #pragma unroll
  for (int nt = 0; nt < 4; ++nt) {
    int col = wn + nt * 16 + lr;
    float bv = bin[col];
    #pragma unroll
    for (int rr = 0; rr < 4; ++rr) {
      int row = wm + lk * 4 + rr;
      float v = accP[nt][rr] + bv;
      v = v / (1.0f + expf(-v));
      q[(size_t)(n0 + row) * 128 + col] = v;
      QS[row * 132 + col] = (f16)v;
    }
  }
  __syncthreads();

  f32x4 accD[4] = {};
  #pragma unroll
  for (int kk = 0; kk < 4; ++kk) {
    f16x8 af = *(const f16x8*)&QS[(wm + lr) * 132 + kk * 32 + lk * 8];
    f16x8 bf[4];
    #pragma unroll
    for (int nt = 0; nt < 4; ++nt)
      bf[nt] = *(const f16x8*)&Wi1[(size_t)(wn + nt * 16 + lr) * 128 + kk * 32 + lk * 8];
    #pragma unroll
    for (int nt = 0; nt < 4; ++nt)
      accD[nt] = __builtin_amdgcn_mfma_f32_16x16x32_f16(af, bf[nt], accD[nt], 0, 0, 0);
  }
  #pragma unroll
  for (int nt = 0; nt < 4; ++nt) {
    int col = wn + nt * 16 + lr;
    float bv = bi1[col];
    #pragma unroll
    for (int rr = 0; rr < 4; ++rr) {
      int row = wm + lk * 4 + rr;
      float v = accD[nt][rr] + bv;
      v = v / (1.0f + expf(-v));
      H2S[row * 132 + col] = (f16)v;
    }
  }
  __syncthreads();

  #pragma unroll
  for (int cc = 0; cc < 3; ++cc) {
    f32x4 accE[4] = {};
    #pragma unroll
    for (int kk = 0; kk < 4; ++kk) {
      f16x8 af = *(const f16x8*)&H2S[(wm + lr) * 132 + kk * 32 + lk * 8];
      f16x8 bf[4];
      #pragma unroll
      for (int nt = 0; nt < 4; ++nt)
        bf[nt] = *(const f16x8*)&Wi2[(size_t)(cc * 128 + wn + nt * 16 + lr) * 128 + kk * 32 + lk * 8];
      #pragma unroll
      for (int nt = 0; nt < 4; ++nt)
        accE[nt] = __builtin_amdgcn_mfma_f32_16x16x32_f16(af, bf[nt], accE[nt], 0, 0, 0);
    }
    #pragma unroll
    for (int nt = 0; nt < 4; ++nt) {
      int gn = cc * 128 + wn + nt * 16 + lr;
      float bv = bi2[gn];
      #pragma unroll
      for (int rr = 0; rr < 4; ++rr) {
        int gm = n0 + wm + lk * 4 + rr;
        xout[(size_t)gm * 384 + gn] = (f16)(accE[nt][rr] + bv);
      }
    }
  }
}

// ======== fused mix phase v3.1: overlapped LDS (25.3 KB), two-half phase A ========
// MODE 0: mix + next inter MLP -> xout. MODE 1: mix + LN+tanh -> out_node.
// LDS timeline: As4 (phase A) -> [barrier] -> VN/HS/QS; H2S overlays VN; QSf overlays VN+HS.
template<int MODE>
__global__ __launch_bounds__(256, 4) void k_mix(
    float* __restrict__ q, f16* __restrict__ mu,
    const f16* __restrict__ Wmu,
    const f16* __restrict__ W1, const float* __restrict__ b1,
    const f16* __restrict__ W2, const float* __restrict__ b2,
    const f16* __restrict__ Wi1, const float* __restrict__ bi1,
    const f16* __restrict__ Wi2, const float* __restrict__ bi2,
    f16* __restrict__ xout,
    const float* __restrict__ ln_g, const float* __restrict__ ln_b,
    float* __restrict__ out_node) {
  __shared__ __align__(16) char pool[25344];
  f16*   As4 = (f16*)pool;                // [4][96][32] = 24576 B (phase A only)
  f16*   VN  = (f16*)pool;                // [32][132] (after barrier)
  f16*   HS  = (f16*)(pool + 8448);       // [32][132]
  f16*   QS  = (f16*)(pool + 16896);      // [32][132] f16 (MODE 0)
  f16*   H2S = (f16*)pool;                // MODE 0 phase D out (VN dead)
  float* QSf = (float*)pool;              // MODE 1 [32][132] f32 (VN+HS dead)

  const int tid = threadIdx.x;
  const int wave = tid >> 6, lane = tid & 63;
  const int lr = lane & 15, lk = lane >> 4;
  const int wm = (wave & 1) * 16;   // node group
  const int wn = (wave >> 1) * 64;  // col group
  const int n0 = blockIdx.x * 32;

  // ---- stage mu tile coalesced: flat f16x8 granules, dir-major LDS rows ----
  #pragma unroll
  for (int rep = 0; rep < 6; ++rep) {
    int idx = rep * 256 + tid;            // 0..1535 granules of 8 f16
    f16x8 v = *(const f16x8*)(mu + (size_t)n0 * 384 + idx * 8);
    int node = idx / 48;
    int g    = idx - node * 48;           // 0..47
    int dir  = g >> 4;
    int kb   = (g >> 2) & 3;
    int c8   = g & 3;
    int row  = dir * 32 + node;           // dir-major
    *(f16x8*)&As4[((kb * 96 + row) << 5) + ((c8 ^ ((row >> 1) & 3)) << 3)] = v;
  }
  __syncthreads();

  // ---- phase A (two halves, <=12 f32x4 accs live at once) ----
  f16 Vp[3][4][4];
  f16 Wp[3][4][4];
  f16 svp[4][4];
  float vnv_[4][4];
  {
    // half V
    f32x4 acc[3][4] = {};
    #pragma unroll
    for (int kk = 0; kk < 4; ++kk) {
      f16x8 af[3];
      #pragma unroll
      for (int mt = 0; mt < 3; ++mt) {
        int r = mt * 32 + wm + lr;
        af[mt] = *(const f16x8*)&As4[((kk * 96 + r) << 5) + ((lk ^ ((r >> 1) & 3)) << 3)];
      }
      #pragma unroll
      for (int nt = 0; nt < 4; ++nt) {
        f16x8 bf = *(const f16x8*)&Wmu[(size_t)(wn + nt * 16 + lr) * 128 + kk * 32 + lk * 8];
        #pragma unroll
        for (int mt = 0; mt < 3; ++mt)
          acc[mt][nt] = __builtin_amdgcn_mfma_f32_16x16x32_f16(af[mt], bf, acc[mt][nt], 0, 0, 0);
      }
    }
    #pragma unroll
    for (int mt = 0; mt < 3; ++mt)
      #pragma unroll
      for (int nt = 0; nt < 4; ++nt)
        #pragma unroll
        for (int rr = 0; rr < 4; ++rr)
          Vp[mt][nt][rr] = (f16)acc[mt][nt][rr];
  }
  {
    // half W
    f32x4 acc[3][4] = {};
    #pragma unroll
    for (int kk = 0; kk < 4; ++kk) {
      f16x8 af[3];
      #pragma unroll
      for (int mt = 0; mt < 3; ++mt) {
        int r = mt * 32 + wm + lr;
        af[mt] = *(const f16x8*)&As4[((kk * 96 + r) << 5) + ((lk ^ ((r >> 1) & 3)) << 3)];
      }
      #pragma unroll
      for (int nt = 0; nt < 4; ++nt) {
        f16x8 bf = *(const f16x8*)&Wmu[(size_t)(128 + wn + nt * 16 + lr) * 128 + kk * 32 + lk * 8];
        #pragma unroll
        for (int mt = 0; mt < 3; ++mt)
          acc[mt][nt] = __builtin_amdgcn_mfma_f32_16x16x32_f16(af[mt], bf, acc[mt][nt], 0, 0, 0);
      }
    }
    #pragma unroll
    for (int nt = 0; nt < 4; ++nt)
      #pragma unroll
      for (int rr = 0; rr < 4; ++rr) {
        float V0 = (float)Vp[0][nt][rr], V1 = (float)Vp[1][nt][rr], V2 = (float)Vp[2][nt][rr];
        float W0 = acc[0][nt][rr], W1v = acc[1][nt][rr], W2v = acc[2][nt][rr];
        Wp[0][nt][rr] = (f16)W0; Wp[1][nt][rr] = (f16)W1v; Wp[2][nt][rr] = (f16)W2v;
        svp[nt][rr] = (f16)(V0 * W0 + V1 * W1v + V2 * W2v);
        vnv_[nt][rr] = sqrtf(V0 * V0 + V1 * V1 + V2 * V2 + 1e-8f);
      }
  }
  __syncthreads();   // all As4 reads done -> VN region reusable

  // ---- write VN (C-frag: node = wm+lk*4+rr, col = wn+nt*16+lr) ----
  #pragma unroll
  for (int nt = 0; nt < 4; ++nt)
    #pragma unroll
    for (int rr = 0; rr < 4; ++rr)
      VN[(wm + lk * 4 + rr) * 132 + wn + nt * 16 + lr] = (f16)vnv_[nt][rr];
  __syncthreads();

  // ---- phase B: h = silu([q|vn] @ W1^T + b1) -> HS ----
  f32x4 accB[4] = {};
  #pragma unroll
  for (int kk = 0; kk < 8; ++kk) {
    f16x8 af;
    if (kk < 4) {
      const float* qp_ = q + (size_t)(n0 + wm + lr) * 128 + kk * 32 + lk * 8;
      float4 v0 = ((const float4*)qp_)[0];
      float4 v1 = ((const float4*)qp_)[1];
      af[0]=(f16)v0.x; af[1]=(f16)v0.y; af[2]=(f16)v0.z; af[3]=(f16)v0.w;
      af[4]=(f16)v1.x; af[5]=(f16)v1.y; af[6]=(f16)v1.z; af[7]=(f16)v1.w;
    } else {
      af = *(const f16x8*)&VN[(wm + lr) * 132 + (kk - 4) * 32 + lk * 8];
    }
    f16x8 bf[4];
    #pragma unroll
    for (int nt = 0; nt < 4; ++nt)
      bf[nt] = *(const f16x8*)&W1[(size_t)(wn + nt * 16 + lr) * 256 + kk * 32 + lk * 8];
    #pragma unroll
    for (int nt = 0; nt < 4; ++nt)
      accB[nt] = __builtin_amdgcn_mfma_f32_16x16x32_f16(af, bf[nt], accB[nt], 0, 0, 0);
  }
  #pragma unroll
  for (int nt = 0; nt < 4; ++nt) {
    int col = wn + nt * 16 + lr;
    float bv = b1[col];
    #pragma unroll
    for (int rr = 0; rr < 4; ++rr) {
      float v = accB[nt][rr] + bv;
      v = v / (1.0f + expf(-v));
      HS[(wm + lk * 4 + rr) * 132 + col] = (f16)v;
    }
  }
  __syncthreads();

  // ---- phase C: xm = h @ W2^T + b2 ----
  f32x4 accC[3][4] = {};
  #pragma unroll
  for (int cc = 0; cc < 3; ++cc)
    #pragma unroll
    for (int kk = 0; kk < 4; ++kk) {
      f16x8 af = *(const f16x8*)&HS[(wm + lr) * 132 + kk * 32 + lk * 8];
      f16x8 bf[4];
      #pragma unroll
      for (int nt = 0; nt < 4; ++nt)
        bf[nt] = *(const f16x8*)&W2[(size_t)(cc * 128 + wn + nt * 16 + lr) * 128 + kk * 32 + lk * 8];
      #pragma unroll
      for (int nt = 0; nt < 4; ++nt)
        accC[cc][nt] = __builtin_amdgcn_mfma_f32_16x16x32_f16(af, bf[nt], accC[cc][nt], 0, 0, 0);
    }
  __syncthreads();   // HS/VN reads done

  // ---- epilogue: q/mu update from registers (svp, Wp) ----
  #pragma unroll
  for (int nt = 0; nt < 4; ++nt) {
    int col = wn + nt * 16 + lr;
    float b_dq = b2[col], b_dmu = b2[128 + col], b_dqmu = b2[256 + col];
    #pragma unroll
    for (int rr = 0; rr < 4; ++rr) {
      int nn = wm + lk * 4 + rr;
      int gm = n0 + nn;
      float dq   = accC[0][nt][rr] + b_dq;
      float dmu  = accC[1][nt][rr] + b_dmu;
      float dqmu = accC[2][nt][rr] + b_dqmu;
      float W0 = (float)Wp[0][nt][rr], W1v = (float)Wp[1][nt][rr], W2v = (float)Wp[2][nt][rr];
      size_t qi = (size_t)gm * 128 + col;
      float qnew = q[qi] + dq + dqmu * (float)svp[nt][rr];
      if constexpr (MODE == 0) {
        q[qi] = qnew;
        QS[nn * 132 + col] = (f16)qnew;
      } else {
        QSf[nn * 132 + col] = qnew;
      }
      f16* mr = mu + (size_t)gm * 384;
      mr[col]       = (f16)((float)mr[col]       + dmu * W0);
      mr[128 + col] = (f16)((float)mr[128 + col] + dmu * W1v);
      mr[256 + col] = (f16)((float)mr[256 + col] + dmu * W2v);
    }
  }
  __syncthreads();

  if constexpr (MODE == 0) {
    // ---- phase D: h2 = silu(QS @ Wi1^T + bi1) -> H2S (VN region, dead) ----
    f32x4 accD[4] = {};
    #pragma unroll
    for (int kk = 0; kk < 4; ++kk) {
      f16x8 af = *(const f16x8*)&QS[(wm + lr) * 132 + kk * 32 + lk * 8];
      f16x8 bf[4];
      #pragma unroll
      for (int nt = 0; nt < 4; ++nt)
        bf[nt] = *(const f16x8*)&Wi1[(size_t)(wn + nt * 16 + lr) * 128 + kk * 32 + lk * 8];
      #pragma unroll
      for (int nt = 0; nt < 4; ++nt)
        accD[nt] = __builtin_amdgcn_mfma_f32_16x16x32_f16(af, bf[nt], accD[nt], 0, 0, 0);
    }
    #pragma unroll
    for (int nt = 0; nt < 4; ++nt) {
      int col = wn + nt * 16 + lr;
      float bv = bi1[col];
      #pragma unroll
      for (int rr = 0; rr < 4; ++rr) {
        float v = accD[nt][rr] + bv;
        v = v / (1.0f + expf(-v));
        H2S[(wm + lk * 4 + rr) * 132 + col] = (f16)v;
      }
    }
    __syncthreads();
    // ---- phase E: x = h2 @ Wi2^T + bi2 ----
    #pragma unroll
    for (int cc = 0; cc < 3; ++cc) {
      f32x4 accE[4] = {};
      #pragma unroll
      for (int kk = 0; kk < 4; ++kk) {
        f16x8 af = *(const f16x8*)&H2S[(wm + lr) * 132 + kk * 32 + lk * 8];
        f16x8 bf[4];
        #pragma unroll
        for (int nt = 0; nt < 4; ++nt)
          bf[nt] = *(const f16x8*)&Wi2[(size_t)(cc * 128 + wn + nt * 16 + lr) * 128 + kk * 32 + lk * 8];
        #pragma unroll
        for (int nt = 0; nt < 4; ++nt)
          accE[nt] = __builtin_amdgcn_mfma_f32_16x16x32_f16(af, bf[nt], accE[nt], 0, 0, 0);
      }
      #pragma unroll
      for (int nt = 0; nt < 4; ++nt) {
        int gn = cc * 128 + wn + nt * 16 + lr;
        float bv = bi2[gn];
        #pragma unroll
        for (int rr = 0; rr < 4; ++rr) {
          int gm = n0 + wm + lk * 4 + rr;
          xout[(size_t)gm * 384 + gn] = (f16)(accE[nt][rr] + bv);
        }
      }
    }
  } else {
    // ---- LayerNorm + tanh on the final q tile ----
    const int d0 = lane * 2;
    #pragma unroll
    for (int rr2 = 0; rr2 < 8; ++rr2) {
      int nn = wave * 8 + rr2;
      float v0 = QSf[nn * 132 + d0];
      float v1 = QSf[nn * 132 + d0 + 1];
      v0 = fminf(fmaxf(v0, -5.f), 5.f);
      v1 = fminf(fmaxf(v1, -5.f), 5.f);
      float s = v0 + v1, s2 = v0 * v0 + v1 * v1;
      #pragma unroll
      for (int off = 32; off > 0; off >>= 1) {
        s  += __shfl_down(s,  off, 64);
        s2 += __shfl_down(s2, off, 64);
      }
      s  = __shfl(s,  0, 64);
      s2 = __shfl(s2, 0, 64);
      float mean = s * (1.0f / 128.0f);
      float var  = s2 * (1.0f / 128.0f) - mean * mean;
      float r = rsqrtf(var + 1e-5f);
      size_t o = (size_t)(n0 + nn) * 128 + d0;
      out_node[o]     = tanhf((v0 - mean) * r * ln_g[d0]     + ln_b[d0]);
      out_node[o + 1] = tanhf((v1 - mean) * r * ln_g[d0 + 1] + ln_b[d0 + 1]);
    }
  }
}

// ---------------- per-node edge reduction (HASMU=false at layer 0: mu==0) ----------------
template<bool HASMU>
__global__ __launch_bounds__(256) void k_edge_msg(
    const int* __restrict__ rs, const int* __restrict__ jperm,
    const f16* __restrict__ x, const f16* __restrict__ tab,
    const float4* __restrict__ geo, const f16* __restrict__ mu_in,
    float* __restrict__ q, f16* __restrict__ mu_out) {
  const int wid  = threadIdx.x >> 6;
  const int lane = threadIdx.x & 63;
  const int i = blockIdx.x * 4 + wid;
  if (i >= N_NODES) return;
  const int d0 = lane * 2;
  const float scale = (float)(TAB_T - 1) / 5.0f;
  float aqx = 0.f, aqy = 0.f;
  float a0x = 0.f, a0y = 0.f, a1x = 0.f, a1y = 0.f, a2x = 0.f, a2y = 0.f;
  const int s = rs[i], e = rs[i + 1];

  for (int p = s; p < e; ++p) {
    int j = jperm[p];
    float4 g = geo[p];
    float u = fminf(g.x, 5.0f) * scale;
    int t0 = min((int)u, TAB_T - 2);
    float fr = u - (float)t0, fo = 1.0f - fr;
    const f16* ta = tab + (size_t)t0 * 384;
    const f16* xj = x + (size_t)j * 384;
    f16x2 ta0 = *(const f16x2*)(ta + d0);
    f16x2 ta1 = *(const f16x2*)(ta + 128 + d0);
    f16x2 tb0 = *(const f16x2*)(ta + 384 + d0);
    f16x2 tb1 = *(const f16x2*)(ta + 512 + d0);
    f16x2 xv0 = *(const f16x2*)(xj + d0);
    f16x2 xv1 = *(const f16x2*)(xj + 128 + d0);
    float W0x = fo * (float)ta0[0] + fr * (float)tb0[0];
    float W0y = fo * (float)ta0[1] + fr * (float)tb0[1];
    float W1x = fo * (float)ta1[0] + fr * (float)tb1[0];
    float W1y = fo * (float)ta1[1] + fr * (float)tb1[1];
    float m1x = (float)xv1[0] * W1x, m1y = (float)xv1[1] * W1y;
    aqx = fmaf((float)xv0[0], W0x, aqx);
    aqy = fmaf((float)xv0[1], W0y, aqy);
    if constexpr (HASMU) {
      f16x2 ta2 = *(const f16x2*)(ta + 256 + d0);
      f16x2 tb2 = *(const f16x2*)(ta + 640 + d0);
      f16x2 xv2 = *(const f16x2*)(xj + 256 + d0);
      const f16* mj = mu_in + (size_t)j * 384;
      f16x2 mv0 = *(const f16x2*)(mj + d0);
      f16x2 mv1 = *(const f16x2*)(mj + 128 + d0);
      f16x2 mv2 = *(const f16x2*)(mj + 256 + d0);
      float W2x = fo * (float)ta2[0] + fr * (float)tb2[0];
      float W2y = fo * (float)ta2[1] + fr * (float)tb2[1];
      float m2x = (float)xv2[0] * W2x, m2y = (float)xv2[1] * W2y;
      a0x += m1x * g.y + m2x * (float)mv0[0];
      a0y += m1y * g.y + m2y * (float)mv0[1];
      a1x += m1x * g.z + m2x * (float)mv1[0];
      a1y += m1y * g.z + m2y * (float)mv1[1];
      a2x += m1x * g.w + m2x * (float)mv2[0];
      a2y += m1y * g.w + m2y * (float)mv2[1];
    } else {
      a0x += m1x * g.y; a0y += m1y * g.y;
      a1x += m1x * g.z; a1y += m1y * g.z;
      a2x += m1x * g.w; a2y += m1y * g.w;
    }
  }

  float* qp = q + (size_t)i * 128 + d0;
  float2 qv = *(float2*)qp;
  qv.x += aqx; qv.y += aqy;
  *(float2*)qp = qv;
  f16* mout = mu_out + (size_t)i * 384;
  f16x2 o0, o1, o2;
  if constexpr (HASMU) {
    const f16* min_ = mu_in + (size_t)i * 384;
    f16x2 i0 = *(const f16x2*)(min_ + d0);
    f16x2 i1 = *(const f16x2*)(min_ + 128 + d0);
    f16x2 i2 = *(const f16x2*)(min_ + 256 + d0);
    o0[0] = (f16)((float)i0[0] + a0x); o0[1] = (f16)((float)i0[1] + a0y);
    o1[0] = (f16)((float)i1[0] + a1x); o1[1] = (f16)((float)i1[1] + a1y);
    o2[0] = (f16)((float)i2[0] + a2x); o2[1] = (f16)((float)i2[1] + a2y);
  } else {
    o0[0] = (f16)a0x; o0[1] = (f16)a0y;
    o1[0] = (f16)a1x; o1[1] = (f16)a1y;
    o2[0] = (f16)a2x; o2[1] = (f16)a2y;
  }
  *(f16x2*)(mout + d0)       = o0;
  *(f16x2*)(mout + 128 + d0) = o1;
  *(f16x2*)(mout + 256 + d0) = o2;
}

// ---------------- pos_attr (per-lane zero-weight skip) ----------------
__global__ __launch_bounds__(256) void k_posattr(
    const int* __restrict__ rs, const int* __restrict__ jperm,
    const f16* __restrict__ mu, const float* __restrict__ w, float* __restrict__ pos_out) {
  const int wid  = threadIdx.x >> 6;
  const int lane = threadIdx.x & 63;
  const int i = blockIdx.x * 4 + wid;
  if (i >= N_NODES) return;
  const int d0 = lane * 2;
  float a0x = 0.f, a0y = 0.f, a1x = 0.f, a1y = 0.f, a2x = 0.f, a2y = 0.f;
  float wx = w[d0], wy = w[d0 + 1];
  if (wx != 0.0f || wy != 0.0f) {
    const int s = rs[i], e = rs[i + 1];
    for (int p = s; p < e; ++p) {
      int j = jperm[p];
      const f16* mj = mu + (size_t)j * 384;
      f16x2 A0 = *(const f16x2*)(mj + d0);
      f16x2 A1 = *(const f16x2*)(mj + 128 + d0);
      f16x2 A2 = *(const f16x2*)(mj + 256 + d0);
      a0x += (float)A0[0]; a0y += (float)A0[1];
      a1x += (float)A1[0]; a1y += (float)A1[1];
      a2x += (float)A2[0]; a2y += (float)A2[1];
    }
  }
  float s0 = fminf(fmaxf(a0x, -5.f), 5.f) * wx + fminf(fmaxf(a0y, -5.f), 5.f) * wy;
  float s1 = fminf(fmaxf(a1x, -5.f), 5.f) * wx + fminf(fmaxf(a1y, -5.f), 5.f) * wy;
  float s2 = fminf(fmaxf(a2x, -5.f), 5.f) * wx + fminf(fmaxf(a2y, -5.f), 5.f) * wy;
  #pragma unroll
  for (int off = 32; off > 0; off >>= 1) {
    s0 += __shfl_down(s0, off, 64);
    s1 += __shfl_down(s1, off, 64);
    s2 += __shfl_down(s2, off, 64);
  }
  if (lane == 0) {
    pos_out[(size_t)i * 3 + 0] = fminf(fmaxf(s0, -5.f), 5.f);
    pos_out[(size_t)i * 3 + 1] = fminf(fmaxf(s1, -5.f), 5.f);
    pos_out[(size_t)i * 3 + 2] = fminf(fmaxf(s2, -5.f), 5.f);
  }
}

extern "C" void kernel_launch(void* const* d_in, const int* in_sizes, int n_in,
                              void* d_out, int out_size, void* d_ws, size_t ws_size,
                              hipStream_t stream) {
  const float* z         = (const float*)d_in[0];
  const float* pos       = (const float*)d_in[1];
  const int*   edge_idx  = (const int*)d_in[2];
  const float* in_w      = (const float*)d_in[3];
  const float* in_b      = (const float*)d_in[4];
  const float* filt_w    = (const float*)d_in[5];
  const float* filt_b    = (const float*)d_in[6];
  const float* inter_w1  = (const float*)d_in[7];
  const float* inter_b1  = (const float*)d_in[8];
  const float* inter_w2  = (const float*)d_in[9];
  const float* inter_b2  = (const float*)d_in[10];
  const float* mix_mu_w  = (const float*)d_in[11];
  const float* mix_w1    = (const float*)d_in[12];
  const float* mix_b1    = (const float*)d_in[13];
  const float* mix_w2    = (const float*)d_in[14];
  const float* mix_b2    = (const float*)d_in[15];
  const float* mu_proj_w = (const float*)d_in[16];
  const float* ln_g      = (const float*)d_in[17];
  const float* ln_b      = (const float*)d_in[18];

  char* base = (char*)d_ws;
  size_t off = 0;
  auto alloc = [&](size_t bytes) -> char* {
    char* p = base + off;
    off += (bytes + 255) & ~(size_t)255;
    return p;
  };
  float*  q     = (float*)alloc((size_t)N_NODES * 128 * 4);
  f16*    x16   = (f16*)alloc((size_t)N_NODES * 384 * 2);
  f16*    mu_a  = (f16*)alloc((size_t)N_NODES * 384 * 2);
  f16*    mu_b  = (f16*)alloc((size_t)N_NODES * 384 * 2);
  float4* geo   = (float4*)alloc((size_t)N_EDGES * 16);
  int*    cnt   = (int*)alloc((size_t)N_NODES * 4);
  int*    incl  = (int*)alloc((size_t)N_NODES * 4);
  int*    bsum  = (int*)alloc(128 * 4);
  int*    rs    = (int*)alloc((size_t)(N_NODES + 1) * 4);
  int*    cur   = (int*)alloc((size_t)N_NODES * 4);
  int*    jperm = (int*)alloc((size_t)N_EDGES * 4);
  f16*    tab   = (f16*)alloc((size_t)TAB_T * 384 * 2);
  f16* wt_in = (f16*)alloc((size_t)128 * 64 * 2);
  f16* wt_i1 = (f16*)alloc((size_t)3 * 128 * 128 * 2);
  f16* wt_i2 = (f16*)alloc((size_t)3 * 384 * 128 * 2);
  f16* wt_mu = (f16*)alloc((size_t)3 * 256 * 128 * 2);
  f16* wt_x1 = (f16*)alloc((size_t)3 * 128 * 256 * 2);
  f16* wt_x2 = (f16*)alloc((size_t)3 * 384 * 128 * 2);
  if (off > ws_size) return;

  float* out_node = (float*)d_out;
  float* out_pos  = (float*)d_out + (size_t)N_NODES * 128;

  // ---- prep: weight transpose (16 jobs) + filter table ----
  {
    WJobs jb;
    int ji = 0;
    jb.j[ji++] = {in_w, wt_in, 6, 128, 0, 128 * 64};
    for (int l = 0; l < 3; ++l)
      jb.j[ji++] = {inter_w1 + (size_t)l*128*128, wt_i1 + (size_t)l*128*128, 7, 128, 0, 128*128};
    for (int l = 0; l < 3; ++l)
      jb.j[ji++] = {inter_w2 + (size_t)l*128*384, wt_i2 + (size_t)l*384*128, 7, 384, 0, 384*128};
    for (int l = 0; l < 3; ++l)
      jb.j[ji++] = {mix_mu_w + (size_t)l*128*256, wt_mu + (size_t)l*256*128, 7, 256, 0, 256*128};
    for (int l = 0; l < 3; ++l)
      jb.j[ji++] = {mix_w1 + (size_t)l*256*128, wt_x1 + (size_t)l*128*256, 8, 128, 0, 128*256};
    for (int l = 0; l < 3; ++l)
      jb.j[ji++] = {mix_w2 + (size_t)l*128*384, wt_x2 + (size_t)l*384*128, 7, 384, 0, 384*128};
    dim3 g(192, 24);
    k_prep<<<g, 256, 0, stream>>>(jb, filt_w, filt_b, tab);
  }

  // ---- CSR build + geometry ----
  hipMemsetAsync(cnt, 0, (size_t)N_NODES * 4, stream);
  k_hist<<<N_EDGES / 256, 256, 0, stream>>>(edge_idx, cnt);
  k_scan_blk<<<NB_SCAN, 256, 0, stream>>>(cnt, incl, bsum);
  k_scan_top<<<1, 128, 0, stream>>>(bsum);
  k_scan_add<<<NB_SCAN, 256, 0, stream>>>(cnt, incl, bsum, rs, cur);
  k_fill_geom<<<N_EDGES / 256, 256, 0, stream>>>(edge_idx, pos, cur, geo, jperm);

  // ---- embed + inter MLP (layer 0) ----
  const int gmx = N_NODES / 32;          // 625
  const int gn4 = (N_NODES + 3) / 4;     // 5000
  k_embed_i<<<gmx, 256, 0, stream>>>(z, wt_in, in_b,
                                     wt_i1, inter_b1, wt_i2, inter_b2, q, x16);

  f16* mu_cur = mu_a;
  f16* mu_nxt = mu_b;
  for (int l = 0; l < NLAYER; ++l) {
    if (l == 0)
      k_edge_msg<false><<<gn4, 256, 0, stream>>>(rs, jperm, x16, tab, geo, mu_cur, q, mu_nxt);
    else
      k_edge_msg<true><<<gn4, 256, 0, stream>>>(rs, jperm, x16, tab, geo, mu_cur, q, mu_nxt);
    { f16* t = mu_cur; mu_cur = mu_nxt; mu_nxt = t; }
    if (l < NLAYER - 1) {
      k_mix<0><<<gmx, 256, 0, stream>>>(q, mu_cur, wt_mu + (size_t)l*256*128,
                                        wt_x1 + (size_t)l*128*256, mix_b1 + (size_t)l*128,
                                        wt_x2 + (size_t)l*384*128, mix_b2 + (size_t)l*384,
                                        wt_i1 + (size_t)(l+1)*128*128, inter_b1 + (size_t)(l+1)*128,
                                        wt_i2 + (size_t)(l+1)*384*128, inter_b2 + (size_t)(l+1)*384,
                                        x16, nullptr, nullptr, nullptr);
    } else {
      k_mix<1><<<gmx, 256, 0, stream>>>(q, mu_cur, wt_mu + (size_t)l*256*128,
                                        wt_x1 + (size_t)l*128*256, mix_b1 + (size_t)l*128,
                                        wt_x2 + (size_t)l*384*128, mix_b2 + (size_t)l*384,
                                        nullptr, nullptr, nullptr, nullptr, nullptr,
                                        ln_g, ln_b, out_node);
    }
  }

  // ---- pos_attr ----
  k_posattr<<<gn4, 256, 0, stream>>>(rs, jperm, mu_cur, mu_proj_w, out_pos);
}

// Round 17
// 546.104 us; speedup vs baseline: 1.1076x; 1.1076x over previous
//
#include <hip/hip_runtime.h>
#include <math.h>

#ifndef M_PI
#define M_PI 3.14159265358979323846
#endif

static constexpr int N_NODES = 20000;
static constexpr int N_EDGES = 320000;
static constexpr int NLAYER  = 3;
static constexpr int NB_SCAN = (N_NODES + 255) / 256;  // 79
static constexpr int TAB_T   = 1024;                   // filter lookup rows (L2-resident)

typedef _Float16 f16;
typedef __attribute__((ext_vector_type(2))) _Float16 f16x2;
typedef __attribute__((ext_vector_type(8))) _Float16 f16x8;
typedef __attribute__((ext_vector_type(4))) float f32x4;

// ---------------- CSR build ----------------
__global__ void k_hist(const int* __restrict__ idx_i, int* __restrict__ cnt) {
  int e = blockIdx.x * 256 + threadIdx.x;
  if (e < N_EDGES) atomicAdd(&cnt[idx_i[e]], 1);
}

__global__ void k_scan_blk(const int* __restrict__ cnt, int* __restrict__ incl,
                           int* __restrict__ bsum) {
  __shared__ int buf[256];
  int t = threadIdx.x;
  int i = blockIdx.x * 256 + t;
  int v = (i < N_NODES) ? cnt[i] : 0;
  buf[t] = v;
  __syncthreads();
  #pragma unroll
  for (int off = 1; off < 256; off <<= 1) {
    int x = (t >= off) ? buf[t - off] : 0;
    __syncthreads();
    buf[t] += x;
    __syncthreads();
  }
  if (i < N_NODES) incl[i] = buf[t];
  if (t == 255) bsum[blockIdx.x] = buf[255];
}

__global__ void k_scan_top(int* __restrict__ bsum) {
  __shared__ int buf[128];
  int t = threadIdx.x;
  int v = (t < NB_SCAN) ? bsum[t] : 0;
  buf[t] = v;
  __syncthreads();
  #pragma unroll
  for (int off = 1; off < 128; off <<= 1) {
    int x = (t >= off) ? buf[t - off] : 0;
    __syncthreads();
    buf[t] += x;
    __syncthreads();
  }
  if (t <= NB_SCAN) bsum[t] = buf[t] - v;  // exclusive; t==NB_SCAN -> total
}

__global__ void k_scan_add(const int* __restrict__ cnt, const int* __restrict__ incl,
                           const int* __restrict__ bsum, int* __restrict__ rs,
                           int* __restrict__ cur) {
  int i = blockIdx.x * 256 + threadIdx.x;
  if (i < N_NODES) {
    int v = bsum[blockIdx.x] + incl[i] - cnt[i];
    rs[i] = v;
    cur[i] = v;
  }
  if (i == 0) rs[N_NODES] = bsum[NB_SCAN];
}

// ---------------- fill + edge geometry (merged): geo = {d, dx, dy, dz} ----------------
__global__ void k_fill_geom(const int* __restrict__ idx_all, const float* __restrict__ pos,
                            int* __restrict__ cur, float4* __restrict__ geo,
                            int* __restrict__ jperm) {
  int e = blockIdx.x * 256 + threadIdx.x;
  if (e >= N_EDGES) return;
  int i = idx_all[e];
  int j = idx_all[N_EDGES + e];
  int p = atomicAdd(&cur[i], 1);
  float rx = pos[j*3+0] - pos[i*3+0];
  float ry = pos[j*3+1] - pos[i*3+1];
  float rz = pos[j*3+2] - pos[i*3+2];
  float d = sqrtf(rx*rx + ry*ry + rz*rz);
  d = fmaxf(d, 1e-8f);
  float inv = 1.0f / d;
  geo[p] = make_float4(d, rx*inv, ry*inv, rz*inv);
  jperm[p] = j;
}

// ---------------- weight transpose + filter table (merged prep) ----------------
struct WJob { const float* src; f16* dst; int kshift; int ld; int col0; int nk; };
struct WJobs { WJob j[16]; };

__global__ __launch_bounds__(256) void k_prep(WJobs jb, const float* __restrict__ filt_w,
                                              const float* __restrict__ filt_b,
                                              f16* __restrict__ tab) {
  if (blockIdx.y < 16) {
    WJob w = jb.j[blockIdx.y];
    int t = blockIdx.x * 256 + threadIdx.x;
    if (t >= w.nk) return;
    int K = 1 << w.kshift;
    int n = t >> w.kshift;
    int k = t & (K - 1);
    w.dst[t] = (f16)w.src[(size_t)k * w.ld + w.col0 + n];
    return;
  }
  if (blockIdx.x >= 128) return;
  const int t = (blockIdx.y - 16) * 128 + blockIdx.x;
  __shared__ float ph[64];
  const int tid = threadIdx.x;
  const float dist = 5.0f * (float)t / (float)(TAB_T - 1);
  const float delta = 5.0f / 63.0f;
  const float coeff = -0.5f / (delta * delta);
  if (tid < 64) {
    float u = dist - delta * (float)tid;
    ph[tid] = expf(coeff * u * u);
  }
  __syncthreads();
  float xc = dist * 0.2f;
  float fc = (xc < 1.0f) ? 0.5f * (cosf((float)M_PI * xc) + 1.0f) : 0.0f;
  for (int n = tid; n < 384; n += 256) {
    float acc = 0.f;
    #pragma unroll
    for (int k = 0; k < 64; ++k) acc += ph[k] * filt_w[k * 384 + n];
    float v = (acc + filt_b[n]) * fc;
    v = fminf(fmaxf(v, -5.0f), 5.0f);
    tab[(size_t)t * 384 + n] = (f16)v;
  }
}

// ======== embed + inter MLP (layer 0) ========
__global__ __launch_bounds__(256) void k_embed_i(
    const float* __restrict__ z, const f16* __restrict__ Win, const float* __restrict__ bin,
    const f16* __restrict__ Wi1, const float* __restrict__ bi1,
    const f16* __restrict__ Wi2, const float* __restrict__ bi2,
    float* __restrict__ q, f16* __restrict__ xout) {
  __shared__ __align__(16) char pool[16896];
  f16* QS  = (f16*)pool;            // [32][132]
  f16* H2S = (f16*)(pool + 8448);   // [32][132]
  const int tid = threadIdx.x;
  const int wave = tid >> 6, lane = tid & 63;
  const int lr = lane & 15, lk = lane >> 4;
  const int wm = (wave & 1) * 16, wn = (wave >> 1) * 64;
  const int n0 = blockIdx.x * 32;

  f32x4 accP[4] = {};
  #pragma unroll
  for (int kk = 0; kk < 2; ++kk) {
    const float* zp = z + (size_t)(n0 + wm + lr) * 64 + kk * 32 + lk * 8;
    float4 v0 = ((const float4*)zp)[0];
    float4 v1 = ((const float4*)zp)[1];
    f16x8 af;
    af[0]=(f16)v0.x; af[1]=(f16)v0.y; af[2]=(f16)v0.z; af[3]=(f16)v0.w;
    af[4]=(f16)v1.x; af[5]=(f16)v1.y; af[6]=(f16)v1.z; af[7]=(f16)v1.w;
    f16x8 bf[4];
    #pragma unroll
    for (int nt = 0; nt < 4; ++nt)
      bf[nt] = *(const f16x8*)&Win[(size_t)(wn + nt * 16 + lr) * 64 + kk * 32 + lk * 8];
    #pragma unroll
    for (int nt = 0; nt < 4; ++nt)
      accP[nt] = __builtin_amdgcn_mfma_f32_16x16x32_f16(af, bf[nt], accP[nt], 0, 0, 0);
  }
  #pragma unroll
  for (int nt = 0; nt < 4; ++nt) {
    int col = wn + nt * 16 + lr;
    float bv = bin[col];
    #pragma unroll
    for (int rr = 0; rr < 4; ++rr) {
      int row = wm + lk * 4 + rr;
      float v = accP[nt][rr] + bv;
      v = v / (1.0f + expf(-v));
      q[(size_t)(n0 + row) * 128 + col] = v;
      QS[row * 132 + col] = (f16)v;
    }
  }
  __syncthreads();

  f32x4 accD[4] = {};
  #pragma unroll
  for (int kk = 0; kk < 4; ++kk) {
    f16x8 af = *(const f16x8*)&QS[(wm + lr) * 132 + kk * 32 + lk * 8];
    f16x8 bf[4];
    #pragma unroll
    for (int nt = 0; nt < 4; ++nt)
      bf[nt] = *(const f16x8*)&Wi1[(size_t)(wn + nt * 16 + lr) * 128 + kk * 32 + lk * 8];
    #pragma unroll
    for (int nt = 0; nt < 4; ++nt)
      accD[nt] = __builtin_amdgcn_mfma_f32_16x16x32_f16(af, bf[nt], accD[nt], 0, 0, 0);
  }
  #pragma unroll
  for (int nt = 0; nt < 4; ++nt) {
    int col = wn + nt * 16 + lr;
    float bv = bi1[col];
    #pragma unroll
    for (int rr = 0; rr < 4; ++rr) {
      int row = wm + lk * 4 + rr;
      float v = accD[nt][rr] + bv;
      v = v / (1.0f + expf(-v));
      H2S[row * 132 + col] = (f16)v;
    }
  }
  __syncthreads();

  #pragma unroll
  for (int cc = 0; cc < 3; ++cc) {
    f32x4 accE[4] = {};
    #pragma unroll
    for (int kk = 0; kk < 4; ++kk) {
      f16x8 af = *(const f16x8*)&H2S[(wm + lr) * 132 + kk * 32 + lk * 8];
      f16x8 bf[4];
      #pragma unroll
      for (int nt = 0; nt < 4; ++nt)
        bf[nt] = *(const f16x8*)&Wi2[(size_t)(cc * 128 + wn + nt * 16 + lr) * 128 + kk * 32 + lk * 8];
      #pragma unroll
      for (int nt = 0; nt < 4; ++nt)
        accE[nt] = __builtin_amdgcn_mfma_f32_16x16x32_f16(af, bf[nt], accE[nt], 0, 0, 0);
    }
    #pragma unroll
    for (int nt = 0; nt < 4; ++nt) {
      int gn = cc * 128 + wn + nt * 16 + lr;
      float bv = bi2[gn];
      #pragma unroll
      for (int rr = 0; rr < 4; ++rr) {
        int gm = n0 + wm + lk * 4 + rr;
        xout[(size_t)gm * 384 + gn] = (f16)(accE[nt][rr] + bv);
      }
    }
  }
}

// ======== fused mix phase (+ next-layer inter MLP or final LayerNorm) ========
// MODE 0: mix + inter MLP (Wi1/Wi2/bi1/bi2, xout). MODE 1: mix + LN+tanh (ln_g/ln_b/out_node).
template<int MODE>
__global__ __launch_bounds__(256) void k_mix(
    float* __restrict__ q, f16* __restrict__ mu,
    const f16* __restrict__ Wmu,
    const f16* __restrict__ W1, const float* __restrict__ b1,
    const f16* __restrict__ W2, const float* __restrict__ b2,
    const f16* __restrict__ Wi1, const float* __restrict__ bi1,
    const f16* __restrict__ Wi2, const float* __restrict__ bi2,
    f16* __restrict__ xout,
    const float* __restrict__ ln_g, const float* __restrict__ ln_b,
    float* __restrict__ out_node) {
  __shared__ __align__(16) char pool[50688 + 25344];
  f16*   MM  = (f16*)pool;              // [96][264]
  char*  scr = pool + 50688;
  f16*   As4 = (f16*)scr;               // [4][96][32] (staging; dead after phase A)
  f16*   VN  = (f16*)scr;               // [4][32][32] (phase B input)
  f16*   HS  = (f16*)(scr + 8448);      // [32][132]  (phase C input)
  f16*   QS  = (f16*)(scr + 16896);     // [32][132] f16 (MODE 0)
  f16*   H2S = (f16*)scr;               // [32][132]  (MODE 0 phase D out)
  float* QSf = (float*)scr;             // [32][132] f32 (MODE 1)

  const int tid = threadIdx.x;
  const int wave = tid >> 6, lane = tid & 63;
  const int lr = lane & 15, lk = lane >> 4;
  const int n0 = blockIdx.x * 32;
  const int r0 = n0 * 3;

  // ---- stage mu rows into As4 (k-block-major, XOR swizzle) ----
  #pragma unroll
  for (int rep = 0; rep < 6; ++rep) {
    int idx = rep * 256 + tid;
    int row = idx >> 4;
    int g   = idx & 15;
    int kb = g >> 2, c8 = g & 3;
    f16x8 v = *(const f16x8*)(mu + (size_t)(r0 + row) * 128 + g * 8);
    *(f16x8*)&As4[((kb * 96 + row) << 5) + ((c8 ^ ((row >> 1) & 3)) << 3)] = v;
  }
  __syncthreads();

  // ---- phase A: MM = mu @ Wmu^T (96 x 256) ----
  const int wmA = (wave & 1) * 48;
  const int wnA0 = (wave >> 1) * 64;
  #pragma unroll
  for (int half = 0; half < 2; ++half) {
    f32x4 accA[3][4] = {};
    #pragma unroll
    for (int kk = 0; kk < 4; ++kk) {
      f16x8 af[3], bf[4];
      #pragma unroll
      for (int mt = 0; mt < 3; ++mt) {
        int r = wmA + mt * 16 + lr;
        af[mt] = *(const f16x8*)&As4[((kk * 96 + r) << 5) + ((lk ^ ((r >> 1) & 3)) << 3)];
      }
      #pragma unroll
      for (int nt = 0; nt < 4; ++nt)
        bf[nt] = *(const f16x8*)&Wmu[(size_t)(half * 128 + wnA0 + nt * 16 + lr) * 128 + kk * 32 + lk * 8];
      #pragma unroll
      for (int mt = 0; mt < 3; ++mt)
        #pragma unroll
        for (int nt = 0; nt < 4; ++nt)
          accA[mt][nt] = __builtin_amdgcn_mfma_f32_16x16x32_f16(af[mt], bf[nt], accA[mt][nt], 0, 0, 0);
    }
    #pragma unroll
    for (int mt = 0; mt < 3; ++mt)
      #pragma unroll
      for (int nt = 0; nt < 4; ++nt) {
        int col = half * 128 + wnA0 + nt * 16 + lr;
        #pragma unroll
        for (int rr = 0; rr < 4; ++rr) {
          int row = wmA + mt * 16 + lk * 4 + rr;
          MM[row * 264 + col] = (f16)accA[mt][nt][rr];
        }
      }
  }
  __syncthreads();

  // ---- vn pass -> VN (XOR-swizzled) ----
  #pragma unroll
  for (int rep = 0; rep < 16; ++rep) {
    int idx = rep * 256 + tid;
    int nn = idx >> 7, c = idx & 127;
    float V0 = (float)MM[(nn * 3 + 0) * 264 + c];
    float V1 = (float)MM[(nn * 3 + 1) * 264 + c];
    float V2 = (float)MM[(nn * 3 + 2) * 264 + c];
    float vnv = sqrtf(V0 * V0 + V1 * V1 + V2 * V2 + 1e-8f);
    int kb = c >> 5, c8 = (c >> 3) & 3, ce = c & 7;
    VN[((kb * 32 + nn) << 5) + ((c8 ^ ((nn >> 1) & 3)) << 3) + ce] = (f16)vnv;
  }
  __syncthreads();

  // ---- phase B: h = silu([q|vn] @ W1^T + b1) -> HS ----
  const int wmB = (wave & 1) * 16, wnB = (wave >> 1) * 64;
  f32x4 accB[4] = {};
  #pragma unroll
  for (int kk = 0; kk < 8; ++kk) {
    f16x8 af;
    int row = wmB + lr;
    if (kk < 4) {
      const float* qp_ = q + (size_t)(n0 + row) * 128 + kk * 32 + lk * 8;
      float4 v0 = ((const float4*)qp_)[0];
      float4 v1 = ((const float4*)qp_)[1];
      af[0]=(f16)v0.x; af[1]=(f16)v0.y; af[2]=(f16)v0.z; af[3]=(f16)v0.w;
      af[4]=(f16)v1.x; af[5]=(f16)v1.y; af[6]=(f16)v1.z; af[7]=(f16)v1.w;
    } else {
      af = *(const f16x8*)&VN[(((kk - 4) * 32 + row) << 5) + ((lk ^ ((row >> 1) & 3)) << 3)];
    }
    f16x8 bf[4];
    #pragma unroll
    for (int nt = 0; nt < 4; ++nt)
      bf[nt] = *(const f16x8*)&W1[(size_t)(wnB + nt * 16 + lr) * 256 + kk * 32 + lk * 8];
    #pragma unroll
    for (int nt = 0; nt < 4; ++nt)
      accB[nt] = __builtin_amdgcn_mfma_f32_16x16x32_f16(af, bf[nt], accB[nt], 0, 0, 0);
  }
  #pragma unroll
  for (int nt = 0; nt < 4; ++nt) {
    int col = wnB + nt * 16 + lr;
    float bv = b1[col];
    #pragma unroll
    for (int rr = 0; rr < 4; ++rr) {
      int row = wmB + lk * 4 + rr;
      float v = accB[nt][rr] + bv;
      v = v / (1.0f + expf(-v));
      HS[row * 132 + col] = (f16)v;
    }
  }
  __syncthreads();

  // ---- phase C: xm = h @ W2^T + b2 ----
  f32x4 accC[3][4] = {};
  #pragma unroll
  for (int cc = 0; cc < 3; ++cc)
    #pragma unroll
    for (int kk = 0; kk < 4; ++kk) {
      f16x8 af = *(const f16x8*)&HS[(wmB + lr) * 132 + kk * 32 + lk * 8];
      f16x8 bf[4];
      #pragma unroll
      for (int nt = 0; nt < 4; ++nt)
        bf[nt] = *(const f16x8*)&W2[(size_t)(cc * 128 + wnB + nt * 16 + lr) * 128 + kk * 32 + lk * 8];
      #pragma unroll
      for (int nt = 0; nt < 4; ++nt)
        accC[cc][nt] = __builtin_amdgcn_mfma_f32_16x16x32_f16(af, bf[nt], accC[cc][nt], 0, 0, 0);
    }
  __syncthreads();  // HS reads done (MODE1's QSf overlaps HS)

  // ---- epilogue: q/mu update; q-tile kept in LDS for the fused tail ----
  #pragma unroll
  for (int nt = 0; nt < 4; ++nt) {
    int col = wnB + nt * 16 + lr;
    float b_dq = b2[col], b_dmu = b2[128 + col], b_dqmu = b2[256 + col];
    #pragma unroll
    for (int rr = 0; rr < 4; ++rr) {
      int nn = wmB + lk * 4 + rr;
      int gm = n0 + nn;
      float dq   = accC[0][nt][rr] + b_dq;
      float dmu  = accC[1][nt][rr] + b_dmu;
      float dqmu = accC[2][nt][rr] + b_dqmu;
      float V0 = (float)MM[(nn * 3 + 0) * 264 + col], W0 = (float)MM[(nn * 3 + 0) * 264 + 128 + col];
      float V1 = (float)MM[(nn * 3 + 1) * 264 + col], W1v = (float)MM[(nn * 3 + 1) * 264 + 128 + col];
      float V2 = (float)MM[(nn * 3 + 2) * 264 + col], W2v = (float)MM[(nn * 3 + 2) * 264 + 128 + col];
      float svw = V0 * W0 + V1 * W1v + V2 * W2v;
      size_t qi = (size_t)gm * 128 + col;
      float qnew = q[qi] + dq + dqmu * svw;
      if constexpr (MODE == 0) {
        q[qi] = qnew;
        QS[nn * 132 + col] = (f16)qnew;
      } else {
        QSf[nn * 132 + col] = qnew;
      }
      f16* mr = mu + (size_t)gm * 384;
      mr[col]       = (f16)((float)mr[col]       + dmu * W0);
      mr[128 + col] = (f16)((float)mr[128 + col] + dmu * W1v);
      mr[256 + col] = (f16)((float)mr[256 + col] + dmu * W2v);
    }
  }
  __syncthreads();

  if constexpr (MODE == 0) {
    // ---- phase D: h2 = silu(QS @ Wi1^T + bi1) -> H2S ----
    f32x4 accD[4] = {};
    #pragma unroll
    for (int kk = 0; kk < 4; ++kk) {
      f16x8 af = *(const f16x8*)&QS[(wmB + lr) * 132 + kk * 32 + lk * 8];
      f16x8 bf[4];
      #pragma unroll
      for (int nt = 0; nt < 4; ++nt)
        bf[nt] = *(const f16x8*)&Wi1[(size_t)(wnB + nt * 16 + lr) * 128 + kk * 32 + lk * 8];
      #pragma unroll
      for (int nt = 0; nt < 4; ++nt)
        accD[nt] = __builtin_amdgcn_mfma_f32_16x16x32_f16(af, bf[nt], accD[nt], 0, 0, 0);
    }
    #pragma unroll
    for (int nt = 0; nt < 4; ++nt) {
      int col = wnB + nt * 16 + lr;
      float bv = bi1[col];
      #pragma unroll
      for (int rr = 0; rr < 4; ++rr) {
        int row = wmB + lk * 4 + rr;
        float v = accD[nt][rr] + bv;
        v = v / (1.0f + expf(-v));
        H2S[row * 132 + col] = (f16)v;
      }
    }
    __syncthreads();
    // ---- phase E: x = h2 @ Wi2^T + bi2 ----
    #pragma unroll
    for (int cc = 0; cc < 3; ++cc) {
      f32x4 accE[4] = {};
      #pragma unroll
      for (int kk = 0; kk < 4; ++kk) {
        f16x8 af = *(const f16x8*)&H2S[(wmB + lr) * 132 + kk * 32 + lk * 8];
        f16x8 bf[4];
        #pragma unroll
        for (int nt = 0; nt < 4; ++nt)
          bf[nt] = *(const f16x8*)&Wi2[(size_t)(cc * 128 + wnB + nt * 16 + lr) * 128 + kk * 32 + lk * 8];
        #pragma unroll
        for (int nt = 0; nt < 4; ++nt)
          accE[nt] = __builtin_amdgcn_mfma_f32_16x16x32_f16(af, bf[nt], accE[nt], 0, 0, 0);
      }
      #pragma unroll
      for (int nt = 0; nt < 4; ++nt) {
        int gn = cc * 128 + wnB + nt * 16 + lr;
        float bv = bi2[gn];
        #pragma unroll
        for (int rr = 0; rr < 4; ++rr) {
          int gm = n0 + wmB + lk * 4 + rr;
          xout[(size_t)gm * 384 + gn] = (f16)(accE[nt][rr] + bv);
        }
      }
    }
  } else {
    // ---- LayerNorm + tanh on the final q tile ----
    const int d0 = lane * 2;
    #pragma unroll
    for (int rr2 = 0; rr2 < 8; ++rr2) {
      int nn = wave * 8 + rr2;
      float v0 = QSf[nn * 132 + d0];
      float v1 = QSf[nn * 132 + d0 + 1];
      v0 = fminf(fmaxf(v0, -5.f), 5.f);
      v1 = fminf(fmaxf(v1, -5.f), 5.f);
      float s = v0 + v1, s2 = v0 * v0 + v1 * v1;
      #pragma unroll
      for (int off = 32; off > 0; off >>= 1) {
        s  += __shfl_down(s,  off, 64);
        s2 += __shfl_down(s2, off, 64);
      }
      s  = __shfl(s,  0, 64);
      s2 = __shfl(s2, 0, 64);
      float mean = s * (1.0f / 128.0f);
      float var  = s2 * (1.0f / 128.0f) - mean * mean;
      float r = rsqrtf(var + 1e-5f);
      size_t o = (size_t)(n0 + nn) * 128 + d0;
      out_node[o]     = tanhf((v0 - mean) * r * ln_g[d0]     + ln_b[d0]);
      out_node[o + 1] = tanhf((v1 - mean) * r * ln_g[d0 + 1] + ln_b[d0 + 1]);
    }
  }
}

// ---------------- per-node edge reduction (HASMU=false at layer 0: mu==0) ----------------
template<bool HASMU>
__global__ __launch_bounds__(256) void k_edge_msg(
    const int* __restrict__ rs, const int* __restrict__ jperm,
    const f16* __restrict__ x, const f16* __restrict__ tab,
    const float4* __restrict__ geo, const f16* __restrict__ mu_in,
    float* __restrict__ q, f16* __restrict__ mu_out) {
  const int wid  = threadIdx.x >> 6;
  const int lane = threadIdx.x & 63;
  const int i = blockIdx.x * 4 + wid;
  if (i >= N_NODES) return;
  const int d0 = lane * 2;
  const float scale = (float)(TAB_T - 1) / 5.0f;
  float aqx = 0.f, aqy = 0.f;
  float a0x = 0.f, a0y = 0.f, a1x = 0.f, a1y = 0.f, a2x = 0.f, a2y = 0.f;
  const int s = rs[i], e = rs[i + 1];

  for (int p = s; p < e; ++p) {
    int j = jperm[p];
    float4 g = geo[p];
    float u = fminf(g.x, 5.0f) * scale;
    int t0 = min((int)u, TAB_T - 2);
    float fr = u - (float)t0, fo = 1.0f - fr;
    const f16* ta = tab + (size_t)t0 * 384;
    const f16* xj = x + (size_t)j * 384;
    f16x2 ta0 = *(const f16x2*)(ta + d0);
    f16x2 ta1 = *(const f16x2*)(ta + 128 + d0);
    f16x2 tb0 = *(const f16x2*)(ta + 384 + d0);
    f16x2 tb1 = *(const f16x2*)(ta + 512 + d0);
    f16x2 xv0 = *(const f16x2*)(xj + d0);
    f16x2 xv1 = *(const f16x2*)(xj + 128 + d0);
    float W0x = fo * (float)ta0[0] + fr * (float)tb0[0];
    float W0y = fo * (float)ta0[1] + fr * (float)tb0[1];
    float W1x = fo * (float)ta1[0] + fr * (float)tb1[0];
    float W1y = fo * (float)ta1[1] + fr * (float)tb1[1];
    float m1x = (float)xv1[0] * W1x, m1y = (float)xv1[1] * W1y;
    aqx = fmaf((float)xv0[0], W0x, aqx);
    aqy = fmaf((float)xv0[1], W0y, aqy);
    if constexpr (HASMU) {
      f16x2 ta2 = *(const f16x2*)(ta + 256 + d0);
      f16x2 tb2 = *(const f16x2*)(ta + 640 + d0);
      f16x2 xv2 = *(const f16x2*)(xj + 256 + d0);
      const f16* mj = mu_in + (size_t)j * 384;
      f16x2 mv0 = *(const f16x2*)(mj + d0);
      f16x2 mv1 = *(const f16x2*)(mj + 128 + d0);
      f16x2 mv2 = *(const f16x2*)(mj + 256 + d0);
      float W2x = fo * (float)ta2[0] + fr * (float)tb2[0];
      float W2y = fo * (float)ta2[1] + fr * (float)tb2[1];
      float m2x = (float)xv2[0] * W2x, m2y = (float)xv2[1] * W2y;
      a0x += m1x * g.y + m2x * (float)mv0[0];
      a0y += m1y * g.y + m2y * (float)mv0[1];
      a1x += m1x * g.z + m2x * (float)mv1[0];
      a1y += m1y * g.z + m2y * (float)mv1[1];
      a2x += m1x * g.w + m2x * (float)mv2[0];
      a2y += m1y * g.w + m2y * (float)mv2[1];
    } else {
      a0x += m1x * g.y; a0y += m1y * g.y;
      a1x += m1x * g.z; a1y += m1y * g.z;
      a2x += m1x * g.w; a2y += m1y * g.w;
    }
  }

  float* qp = q + (size_t)i * 128 + d0;
  float2 qv = *(float2*)qp;
  qv.x += aqx; qv.y += aqy;
  *(float2*)qp = qv;
  f16* mout = mu_out + (size_t)i * 384;
  f16x2 o0, o1, o2;
  if constexpr (HASMU) {
    const f16* min_ = mu_in + (size_t)i * 384;
    f16x2 i0 = *(const f16x2*)(min_ + d0);
    f16x2 i1 = *(const f16x2*)(min_ + 128 + d0);
    f16x2 i2 = *(const f16x2*)(min_ + 256 + d0);
    o0[0] = (f16)((float)i0[0] + a0x); o0[1] = (f16)((float)i0[1] + a0y);
    o1[0] = (f16)((float)i1[0] + a1x); o1[1] = (f16)((float)i1[1] + a1y);
    o2[0] = (f16)((float)i2[0] + a2x); o2[1] = (f16)((float)i2[1] + a2y);
  } else {
    o0[0] = (f16)a0x; o0[1] = (f16)a0y;
    o1[0] = (f16)a1x; o1[1] = (f16)a1y;
    o2[0] = (f16)a2x; o2[1] = (f16)a2y;
  }
  *(f16x2*)(mout + d0)       = o0;
  *(f16x2*)(mout + 128 + d0) = o1;
  *(f16x2*)(mout + 256 + d0) = o2;
}

// ---------------- pos_attr (per-lane zero-weight skip) ----------------
__global__ __launch_bounds__(256) void k_posattr(
    const int* __restrict__ rs, const int* __restrict__ jperm,
    const f16* __restrict__ mu, const float* __restrict__ w, float* __restrict__ pos_out) {
  const int wid  = threadIdx.x >> 6;
  const int lane = threadIdx.x & 63;
  const int i = blockIdx.x * 4 + wid;
  if (i >= N_NODES) return;
  const int d0 = lane * 2;
  float a0x = 0.f, a0y = 0.f, a1x = 0.f, a1y = 0.f, a2x = 0.f, a2y = 0.f;
  float wx = w[d0], wy = w[d0 + 1];
  if (wx != 0.0f || wy != 0.0f) {
    const int s = rs[i], e = rs[i + 1];
    for (int p = s; p < e; ++p) {
      int j = jperm[p];
      const f16* mj = mu + (size_t)j * 384;
      f16x2 A0 = *(const f16x2*)(mj + d0);
      f16x2 A1 = *(const f16x2*)(mj + 128 + d0);
      f16x2 A2 = *(const f16x2*)(mj + 256 + d0);
      a0x += (float)A0[0]; a0y += (float)A0[1];
      a1x += (float)A1[0]; a1y += (float)A1[1];
      a2x += (float)A2[0]; a2y += (float)A2[1];
    }
  }
  float s0 = fminf(fmaxf(a0x, -5.f), 5.f) * wx + fminf(fmaxf(a0y, -5.f), 5.f) * wy;
  float s1 = fminf(fmaxf(a1x, -5.f), 5.f) * wx + fminf(fmaxf(a1y, -5.f), 5.f) * wy;
  float s2 = fminf(fmaxf(a2x, -5.f), 5.f) * wx + fminf(fmaxf(a2y, -5.f), 5.f) * wy;
  #pragma unroll
  for (int off = 32; off > 0; off >>= 1) {
    s0 += __shfl_down(s0, off, 64);
    s1 += __shfl_down(s1, off, 64);
    s2 += __shfl_down(s2, off, 64);
  }
  if (lane == 0) {
    pos_out[(size_t)i * 3 + 0] = fminf(fmaxf(s0, -5.f), 5.f);
    pos_out[(size_t)i * 3 + 1] = fminf(fmaxf(s1, -5.f), 5.f);
    pos_out[(size_t)i * 3 + 2] = fminf(fmaxf(s2, -5.f), 5.f);
  }
}

extern "C" void kernel_launch(void* const* d_in, const int* in_sizes, int n_in,
                              void* d_out, int out_size, void* d_ws, size_t ws_size,
                              hipStream_t stream) {
  const float* z         = (const float*)d_in[0];
  const float* pos       = (const float*)d_in[1];
  const int*   edge_idx  = (const int*)d_in[2];
  const float* in_w      = (const float*)d_in[3];
  const float* in_b      = (const float*)d_in[4];
  const float* filt_w    = (const float*)d_in[5];
  const float* filt_b    = (const float*)d_in[6];
  const float* inter_w1  = (const float*)d_in[7];
  const float* inter_b1  = (const float*)d_in[8];
  const float* inter_w2  = (const float*)d_in[9];
  const float* inter_b2  = (const float*)d_in[10];
  const float* mix_mu_w  = (const float*)d_in[11];
  const float* mix_w1    = (const float*)d_in[12];
  const float* mix_b1    = (const float*)d_in[13];
  const float* mix_w2    = (const float*)d_in[14];
  const float* mix_b2    = (const float*)d_in[15];
  const float* mu_proj_w = (const float*)d_in[16];
  const float* ln_g      = (const float*)d_in[17];
  const float* ln_b      = (const float*)d_in[18];

  char* base = (char*)d_ws;
  size_t off = 0;
  auto alloc = [&](size_t bytes) -> char* {
    char* p = base + off;
    off += (bytes + 255) & ~(size_t)255;
    return p;
  };
  float*  q     = (float*)alloc((size_t)N_NODES * 128 * 4);
  f16*    x16   = (f16*)alloc((size_t)N_NODES * 384 * 2);
  f16*    mu_a  = (f16*)alloc((size_t)N_NODES * 384 * 2);
  f16*    mu_b  = (f16*)alloc((size_t)N_NODES * 384 * 2);
  float4* geo   = (float4*)alloc((size_t)N_EDGES * 16);
  int*    cnt   = (int*)alloc((size_t)N_NODES * 4);
  int*    incl  = (int*)alloc((size_t)N_NODES * 4);
  int*    bsum  = (int*)alloc(128 * 4);
  int*    rs    = (int*)alloc((size_t)(N_NODES + 1) * 4);
  int*    cur   = (int*)alloc((size_t)N_NODES * 4);
  int*    jperm = (int*)alloc((size_t)N_EDGES * 4);
  f16*    tab   = (f16*)alloc((size_t)TAB_T * 384 * 2);
  f16* wt_in = (f16*)alloc((size_t)128 * 64 * 2);
  f16* wt_i1 = (f16*)alloc((size_t)3 * 128 * 128 * 2);
  f16* wt_i2 = (f16*)alloc((size_t)3 * 384 * 128 * 2);
  f16* wt_mu = (f16*)alloc((size_t)3 * 256 * 128 * 2);
  f16* wt_x1 = (f16*)alloc((size_t)3 * 128 * 256 * 2);
  f16* wt_x2 = (f16*)alloc((size_t)3 * 384 * 128 * 2);
  if (off > ws_size) return;

  float* out_node = (float*)d_out;
  float* out_pos  = (float*)d_out + (size_t)N_NODES * 128;

  // ---- prep: weight transpose (16 jobs) + filter table ----
  {
    WJobs jb;
    int ji = 0;
    jb.j[ji++] = {in_w, wt_in, 6, 128, 0, 128 * 64};
    for (int l = 0; l < 3; ++l)
      jb.j[ji++] = {inter_w1 + (size_t)l*128*128, wt_i1 + (size_t)l*128*128, 7, 128, 0, 128*128};
    for (int l = 0; l < 3; ++l)
      jb.j[ji++] = {inter_w2 + (size_t)l*128*384, wt_i2 + (size_t)l*384*128, 7, 384, 0, 384*128};
    for (int l = 0; l < 3; ++l)
      jb.j[ji++] = {mix_mu_w + (size_t)l*128*256, wt_mu + (size_t)l*256*128, 7, 256, 0, 256*128};
    for (int l = 0; l < 3; ++l)
      jb.j[ji++] = {mix_w1 + (size_t)l*256*128, wt_x1 + (size_t)l*128*256, 8, 128, 0, 128*256};
    for (int l = 0; l < 3; ++l)
      jb.j[ji++] = {mix_w2 + (size_t)l*128*384, wt_x2 + (size_t)l*384*128, 7, 384, 0, 384*128};
    dim3 g(192, 24);  // y<16: wt jobs; y>=16: tab rows (8 x 128)
    k_prep<<<g, 256, 0, stream>>>(jb, filt_w, filt_b, tab);
  }

  // ---- CSR build + geometry ----
  hipMemsetAsync(cnt, 0, (size_t)N_NODES * 4, stream);
  k_hist<<<N_EDGES / 256, 256, 0, stream>>>(edge_idx, cnt);
  k_scan_blk<<<NB_SCAN, 256, 0, stream>>>(cnt, incl, bsum);
  k_scan_top<<<1, 128, 0, stream>>>(bsum);
  k_scan_add<<<NB_SCAN, 256, 0, stream>>>(cnt, incl, bsum, rs, cur);
  k_fill_geom<<<N_EDGES / 256, 256, 0, stream>>>(edge_idx, pos, cur, geo, jperm);

  // ---- embed + inter MLP (layer 0) ----
  const int gmx = N_NODES / 32;          // 625
  const int gn4 = (N_NODES + 3) / 4;     // 5000
  k_embed_i<<<gmx, 256, 0, stream>>>(z, wt_in, in_b,
                                     wt_i1, inter_b1, wt_i2, inter_b2, q, x16);

  f16* mu_cur = mu_a;
  f16* mu_nxt = mu_b;
  for (int l = 0; l < NLAYER; ++l) {
    if (l == 0)
      k_edge_msg<false><<<gn4, 256, 0, stream>>>(rs, jperm, x16, tab, geo, mu_cur, q, mu_nxt);
    else
      k_edge_msg<true><<<gn4, 256, 0, stream>>>(rs, jperm, x16, tab, geo, mu_cur, q, mu_nxt);
    { f16* t = mu_cur; mu_cur = mu_nxt; mu_nxt = t; }
    if (l < NLAYER - 1) {
      k_mix<0><<<gmx, 256, 0, stream>>>(q, mu_cur, wt_mu + (size_t)l*256*128,
                                        wt_x1 + (size_t)l*128*256, mix_b1 + (size_t)l*128,
                                        wt_x2 + (size_t)l*384*128, mix_b2 + (size_t)l*384,
                                        wt_i1 + (size_t)(l+1)*128*128, inter_b1 + (size_t)(l+1)*128,
                                        wt_i2 + (size_t)(l+1)*384*128, inter_b2 + (size_t)(l+1)*384,
                                        x16, nullptr, nullptr, nullptr);
    } else {
      k_mix<1><<<gmx, 256, 0, stream>>>(q, mu_cur, wt_mu + (size_t)l*256*128,
                                        wt_x1 + (size_t)l*128*256, mix_b1 + (size_t)l*128,
                                        wt_x2 + (size_t)l*384*128, mix_b2 + (size_t)l*384,
                                        nullptr, nullptr, nullptr, nullptr, nullptr,
                                        ln_g, ln_b, out_node);
    }
  }

  // ---- pos_attr ----
  k_posattr<<<gn4, 256, 0, stream>>>(rs, jperm, mu_cur, mu_proj_w, out_pos);
}